// Round 4
// baseline (215.856 us; speedup 1.0000x reference)
//
#include <hip/hip_runtime.h>
#include <math.h>

// Problem dims (fixed by setup_inputs)
#define B_N 256
#define C_N 1152
#define I_N 8
#define N_N 10
#define D_N 16

constexpr int C_CHUNKS = 48;             // parallelism over the c-reduction
constexpr int C_PER    = C_N / C_CHUNKS; // 24
constexpr int KC       = 4;              // c's staged per round (2 per parity, balanced)
constexpr int ROUNDS   = C_PER / KC;     // 6
constexpr int B_TILE   = 16;             // batch elements per block
constexpr int BLOCK    = 256;
constexpr int WS_STRIDE = 132;           // 128+4: slots 0..7 -> banks distinct
constexpr int WS_PER_C  = N_N * WS_STRIDE;  // 1320
constexpr int XS_STRIDE = C_PER * I_N + 4;  // 196
constexpr int CB_STRIDE = 164;           // comb row stride (2-way max = free)

// ws layout: vsum [B,N,D] floats, then p_s [C_CHUNKS][B][N][D] floats (~8.03 MB)

// R4: RB=2 over b (each lane: bl and bl+4) + warp c-parity split -> halves LDS
// read issue per useful (b,n,c). R3's float2 economy keeps VGPR ~120 (<128 cliff,
// unlike R2's 212). W staged in NATURAL layout with float4 writes (kills the
// stride-2 scalar-write conflicts); d-pair packing happens in registers.
template <bool FIRST>
__global__ __launch_bounds__(BLOCK, 4)
void route_pass(const float* __restrict__ x, const float* __restrict__ W,
                const float* __restrict__ vsum, float* __restrict__ p_s)
{
    __shared__ float xs[B_TILE * XS_STRIDE];   // 12544 B
    __shared__ float Ws[KC * WS_PER_C];        // 21120 B
    __shared__ float comb[B_TILE * CB_STRIDE]; // 10496 B

    const int tid    = threadIdx.x;
    const int warp   = tid >> 6;
    const int lane   = tid & 63;
    const int b_lane = lane & 3;
    const int slot   = lane >> 2;
    const int parity = warp & 1;     // which cc's this warp computes
    const int b_oct  = warp >> 1;    // which 8 b's this warp covers
    const bool active = (slot < N_N);
    const int  n     = active ? slot : (N_N - 1);  // idle lanes shadow n=9 (broadcast)
    const int  chunk = blockIdx.x;
    const int  gb0   = blockIdx.y * B_TILE;
    const int  bl1   = b_oct * 8 + b_lane;
    const int  bl2   = bl1 + 4;
    const int  gb1   = gb0 + bl1;
    const int  gb2   = gb0 + bl2;
    const int  cbase = chunk * C_PER;

    // ---- stage x tile once (coalesced float4) ----
    {
        const float4* x4 = reinterpret_cast<const float4*>(x);
        for (int f = tid; f < (B_TILE * C_PER * I_N) / 4; f += BLOCK) {
            const int e   = f * 4;
            const int b2  = e / (C_PER * I_N);
            const int off = e - b2 * (C_PER * I_N);
            float4 v = x4[(size_t)(gb0 + b2) * (C_N * I_N / 4) + (size_t)cbase * 2 + (off >> 2)];
            *reinterpret_cast<float4*>(&xs[b2 * XS_STRIDE + off]) = v;
        }
    }

    // ---- vsum fragments, d-pair float2 layout (2 b's) ----
    float2 vs1[8], vs2[8];
    if (!FIRST) {
        const float4* vp1 = reinterpret_cast<const float4*>(vsum + ((size_t)gb1 * N_N + n) * D_N);
        const float4* vp2 = reinterpret_cast<const float4*>(vsum + ((size_t)gb2 * N_N + n) * D_N);
        #pragma unroll
        for (int q = 0; q < 4; ++q) {
            float4 a = vp1[q];
            vs1[q * 2]     = make_float2(a.x, a.y);
            vs1[q * 2 + 1] = make_float2(a.z, a.w);
            float4 b = vp2[q];
            vs2[q * 2]     = make_float2(b.x, b.y);
            vs2[q * 2 + 1] = make_float2(b.z, b.w);
        }
    }

    float2 s1[8], s2[8];
    #pragma unroll
    for (int d2 = 0; d2 < 8; ++d2) { s1[d2] = make_float2(0.f, 0.f); s2[d2] = make_float2(0.f, 0.f); }

    const float4* W4 = reinterpret_cast<const float4*>(W);

    for (int round = 0; round < ROUNDS; ++round) {
        __syncthreads();
        // ---- stage W for KC c's, NATURAL layout, float4 writes (no scalar scatter) ----
        const int c0 = cbase + round * KC;
        for (int f = tid; f < (KC * N_N * 128) / 4; f += BLOCK) {
            const int e  = f * 4;
            const int cc = e / (N_N * 128);
            const int r  = e - cc * (N_N * 128);
            const int nn = r >> 7;
            const int k  = r & 127;
            float4 v = W4[(size_t)nn * (C_N * 128 / 4) + (size_t)(c0 + cc) * 32 + (k >> 2)];
            *reinterpret_cast<float4*>(&Ws[cc * WS_PER_C + nn * WS_STRIDE + k]) = v;
        }
        __syncthreads();

        // this warp computes ccl = parity, parity+2 within the round
        #pragma unroll
        for (int half = 0; half < KC / 2; ++half) {
            const int ccl  = half * 2 + parity;
            const int crel = round * KC + ccl;
            const float* xp1 = &xs[bl1 * XS_STRIDE + crel * I_N];
            const float* xp2 = &xs[bl2 * XS_STRIDE + crel * I_N];
            const float4 xa1 = *reinterpret_cast<const float4*>(xp1);
            const float4 xb1 = *reinterpret_cast<const float4*>(xp1 + 4);
            const float4 xa2 = *reinterpret_cast<const float4*>(xp2);
            const float4 xb2 = *reinterpret_cast<const float4*>(xp2 + 4);
            const float* wp = &Ws[ccl * WS_PER_C + n * WS_STRIDE];

            float2 u1[8], u2[8];
            #pragma unroll
            for (int d2 = 0; d2 < 8; ++d2) {
                // row d=2*d2 at wp+d2*16, row d+1 at wp+d2*16+8 (natural layout)
                const float4 q0 = *reinterpret_cast<const float4*>(wp + d2 * 16);      // d,   i0..3
                const float4 q1 = *reinterpret_cast<const float4*>(wp + d2 * 16 + 4);  // d,   i4..7
                const float4 q2 = *reinterpret_cast<const float4*>(wp + d2 * 16 + 8);  // d+1, i0..3
                const float4 q3 = *reinterpret_cast<const float4*>(wp + d2 * 16 + 12); // d+1, i4..7
                float ax, ay, bx, by;
                ax = q0.x * xa1.x;            ay = q2.x * xa1.x;
                ax = fmaf(q0.y, xa1.y, ax);   ay = fmaf(q2.y, xa1.y, ay);
                ax = fmaf(q0.z, xa1.z, ax);   ay = fmaf(q2.z, xa1.z, ay);
                ax = fmaf(q0.w, xa1.w, ax);   ay = fmaf(q2.w, xa1.w, ay);
                ax = fmaf(q1.x, xb1.x, ax);   ay = fmaf(q3.x, xb1.x, ay);
                ax = fmaf(q1.y, xb1.y, ax);   ay = fmaf(q3.y, xb1.y, ay);
                ax = fmaf(q1.z, xb1.z, ax);   ay = fmaf(q3.z, xb1.z, ay);
                ax = fmaf(q1.w, xb1.w, ax);   ay = fmaf(q3.w, xb1.w, ay);
                u1[d2] = make_float2(ax, ay);
                bx = q0.x * xa2.x;            by = q2.x * xa2.x;
                bx = fmaf(q0.y, xa2.y, bx);   by = fmaf(q2.y, xa2.y, by);
                bx = fmaf(q0.z, xa2.z, bx);   by = fmaf(q2.z, xa2.z, by);
                bx = fmaf(q0.w, xa2.w, bx);   by = fmaf(q2.w, xa2.w, by);
                bx = fmaf(q1.x, xb2.x, bx);   by = fmaf(q3.x, xb2.x, by);
                bx = fmaf(q1.y, xb2.y, bx);   by = fmaf(q3.y, xb2.y, by);
                bx = fmaf(q1.z, xb2.z, bx);   by = fmaf(q3.z, xb2.z, by);
                bx = fmaf(q1.w, xb2.w, bx);   by = fmaf(q3.w, xb2.w, by);
                u2[d2] = make_float2(bx, by);
            }

            float c1, c2;
            if (FIRST) {
                c1 = 0.1f; c2 = 0.1f;
            } else {
                float l1x = 0.f, l1y = 0.f, l2x = 0.f, l2y = 0.f;
                #pragma unroll
                for (int d2 = 0; d2 < 8; ++d2) {
                    l1x = fmaf(u1[d2].x, vs1[d2].x, l1x);
                    l1y = fmaf(u1[d2].y, vs1[d2].y, l1y);
                    l2x = fmaf(u2[d2].x, vs2[d2].x, l2x);
                    l2y = fmaf(u2[d2].y, vs2[d2].y, l2y);
                }
                // |logit| <~ 3 -> exp safe without max subtraction
                const float e1 = active ? __expf(l1x + l1y) : 0.f;
                const float e2 = active ? __expf(l2x + l2y) : 0.f;
                float Z1 = e1, Z2 = e2;
                #pragma unroll
                for (int off = 4; off < 64; off <<= 1) {
                    Z1 += __shfl_xor(Z1, off);
                    Z2 += __shfl_xor(Z2, off);
                }
                c1 = e1 * __builtin_amdgcn_rcpf(Z1);
                c2 = e2 * __builtin_amdgcn_rcpf(Z2);
            }
            #pragma unroll
            for (int d2 = 0; d2 < 8; ++d2) {
                s1[d2].x = fmaf(c1, u1[d2].x, s1[d2].x);
                s1[d2].y = fmaf(c1, u1[d2].y, s1[d2].y);
                s2[d2].x = fmaf(c2, u2[d2].x, s2[d2].x);
                s2[d2].y = fmaf(c2, u2[d2].y, s2[d2].y);
            }
        }
    }

    // ---- combine parity-1 partials into parity-0 via LDS, store p_s ----
    __syncthreads();
    if (parity == 1 && active) {
        float* cp1 = &comb[bl1 * CB_STRIDE + n * D_N];
        float* cp2 = &comb[bl2 * CB_STRIDE + n * D_N];
        #pragma unroll
        for (int q = 0; q < 4; ++q) {
            *reinterpret_cast<float4*>(cp1 + q * 4) =
                make_float4(s1[q*2].x, s1[q*2].y, s1[q*2+1].x, s1[q*2+1].y);
            *reinterpret_cast<float4*>(cp2 + q * 4) =
                make_float4(s2[q*2].x, s2[q*2].y, s2[q*2+1].x, s2[q*2+1].y);
        }
    }
    __syncthreads();
    if (parity == 0 && active) {
        const float* cp1 = &comb[bl1 * CB_STRIDE + n * D_N];
        const float* cp2 = &comb[bl2 * CB_STRIDE + n * D_N];
        float* op1 = &p_s[(((size_t)chunk * B_N + gb1) * N_N + n) * D_N];
        float* op2 = &p_s[(((size_t)chunk * B_N + gb2) * N_N + n) * D_N];
        #pragma unroll
        for (int q = 0; q < 4; ++q) {
            float4 a = *reinterpret_cast<const float4*>(cp1 + q * 4);
            float4 b = *reinterpret_cast<const float4*>(cp2 + q * 4);
            *reinterpret_cast<float4*>(op1 + q * 4) =
                make_float4(s1[q*2].x + a.x, s1[q*2].y + a.y, s1[q*2+1].x + a.z, s1[q*2+1].y + a.w);
            *reinterpret_cast<float4*>(op2 + q * 4) =
                make_float4(s2[q*2].x + b.x, s2[q*2].y + b.y, s2[q*2+1].x + b.z, s2[q*2+1].y + b.w);
        }
    }
}

// Parallel reduce+squash: wave per group (b*10+n). lane = h*4+q; h indexes 16
// chunk-slices (3 serial each), q indexes float4 over d. Shuffle-tree over h,
// tiny q-shuffle for |s|^2. phase0 vsum=v; phase1 vsum+=v; phase2 out=v.
__global__ __launch_bounds__(BLOCK)
void reduce_squash(const float* __restrict__ p_s, float* __restrict__ vsum,
                   float* __restrict__ out, int phase)
{
    const int warp = threadIdx.x >> 6;
    const int lane = threadIdx.x & 63;
    const int g    = blockIdx.x * 4 + warp;   // 0..2559 == b*10+n
    const int q    = lane & 3;
    const int h    = lane >> 2;

    float4 s = make_float4(0.f, 0.f, 0.f, 0.f);
    #pragma unroll
    for (int m = 0; m < C_CHUNKS / 16; ++m) {
        const int cc = h + 16 * m;
        float4 v = *reinterpret_cast<const float4*>(
            &p_s[((size_t)cc * (B_N * N_N) + g) * D_N + q * 4]);
        s.x += v.x; s.y += v.y; s.z += v.z; s.w += v.w;
    }
    #pragma unroll
    for (int off = 4; off < 64; off <<= 1) {
        s.x += __shfl_xor(s.x, off);
        s.y += __shfl_xor(s.y, off);
        s.z += __shfl_xor(s.z, off);
        s.w += __shfl_xor(s.w, off);
    }
    float sq = s.x * s.x + s.y * s.y + s.z * s.z + s.w * s.w;
    sq += __shfl_xor(sq, 1);
    sq += __shfl_xor(sq, 2);

    const float scale = (sq / (1.f + sq)) / (sqrtf(sq) + 1e-8f);
    const float4 v = make_float4(scale * s.x, scale * s.y, scale * s.z, scale * s.w);

    if (h == 0) {
        if (phase == 0) {
            *reinterpret_cast<float4*>(&vsum[(size_t)g * D_N + q * 4]) = v;
        } else if (phase == 1) {
            float4 o = *reinterpret_cast<const float4*>(&vsum[(size_t)g * D_N + q * 4]);
            *reinterpret_cast<float4*>(&vsum[(size_t)g * D_N + q * 4]) =
                make_float4(o.x + v.x, o.y + v.y, o.z + v.z, o.w + v.w);
        } else {
            *reinterpret_cast<float4*>(&out[(size_t)g * D_N + q * 4]) = v;
        }
    }
}

extern "C" void kernel_launch(void* const* d_in, const int* in_sizes, int n_in,
                              void* d_out, int out_size, void* d_ws, size_t ws_size,
                              hipStream_t stream)
{
    const float* x = (const float*)d_in[0];
    const float* W = (const float*)d_in[1];
    float* out  = (float*)d_out;
    float* vsum = (float*)d_ws;                         // B*N*D floats
    float* p_s  = vsum + (size_t)B_N * N_N * D_N;       // C_CHUNKS*B*N*D floats

    dim3 grid(C_CHUNKS, B_N / B_TILE);
    dim3 blk(BLOCK);
    dim3 rgrid((B_N * N_N) / 4);                        // 640 blocks, wave per group

    // pass 0: coef = 1/N (softmax of zero logits) -> v0
    route_pass<true><<<grid, blk, 0, stream>>>(x, W, nullptr, p_s);
    reduce_squash<<<rgrid, blk, 0, stream>>>(p_s, vsum, out, 0);
    // pass 1: logits = dot(u_hat, v0) -> v1, vsum = v0+v1
    route_pass<false><<<grid, blk, 0, stream>>>(x, W, vsum, p_s);
    reduce_squash<<<rgrid, blk, 0, stream>>>(p_s, vsum, out, 1);
    // pass 2: logits = dot(u_hat, v0+v1) -> output v2
    route_pass<false><<<grid, blk, 0, stream>>>(x, W, vsum, p_s);
    reduce_squash<<<rgrid, blk, 0, stream>>>(p_s, vsum, out, 2);
}

// Round 5
// 136.581 us; speedup vs baseline: 1.5804x; 1.5804x over previous
//
#include <hip/hip_runtime.h>
#include <math.h>
#include <stdint.h>

// Problem dims (fixed by setup_inputs)
#define B_N 256
#define C_N 1152
#define I_N 8
#define N_N 10
#define D_N 16

constexpr int C_CHUNKS = 48;             // parallelism over the c-reduction
constexpr int C_PER    = 24;             // c's per block
constexpr int STAGE_C  = 8;              // c's per W staging round
constexpr int N_STAGES = 3;
constexpr int B_TILE   = 16;             // batch elements per block (one MFMA tile)
constexpr int BLOCK    = 256;

typedef short v8s __attribute__((ext_vector_type(8)));   // 8 bf16 (4 VGPRs) MFMA A/B frag
typedef float v4f __attribute__((ext_vector_type(4)));   // 4 f32 MFMA C/D frag

// LDS pool (bytes):
//   Ws  (short): [8c][10n][16d][8i]   c-stride 1280 shorts  -> 20480 B @ 0
//   xs  (short): [16b][200]  (24c*8i + 8 pad)               ->  6400 B @ 20480
//   cfl (float): [8c][163]   (10n*16b + 3 pad)              ->  5216 B @ 26880
//   comb(float): [16b][163]  ALIASES xs+cfl                 -> 10432 B @ 20480
constexpr int POOL_BYTES = 20480 + 6400 + 5216;  // 32096 -> 4 blocks/CU

__device__ __forceinline__ uint32_t bf16_rne(float f) {
    uint32_t u = __float_as_uint(f);
    return (u + 0x7FFFu + ((u >> 16) & 1u)) >> 16;
}
__device__ __forceinline__ uint32_t pack2(float a, float b) {
    return bf16_rne(a) | (bf16_rne(b) << 16);
}
__device__ __forceinline__ float bf2f(short s) {
    return __uint_as_float(((uint32_t)(uint16_t)s) << 16);
}

// One routing pass via MFMA. D[row=(lane>>4)*4+reg -> d][col=lane&15 -> b].
// Sweep1: per (c,n) one K-padded MFMA -> u[d,b]; logit = u . vsum (regs) + 2 shfl;
//         per-lane softmax over n (no max-sub: |l| <~ 3); coef -> LDS.
// Sweep2: K=32 packs 4c x 8i (full K); B-frag = bf16(coef*x) built in regs;
//         s[d,b] accumulates in C-frag per n (waves own n-subsets) over all 24 c.
// FIRST: coef = 0.1 (softmax of zeros) -> sweep2 only, no vsum read.
template <bool FIRST>
__global__ __launch_bounds__(BLOCK, 4)
void route_pass(const float* __restrict__ x, const float* __restrict__ W,
                const float* __restrict__ vsum, float* __restrict__ p_s)
{
    __shared__ __align__(16) char pool[POOL_BYTES];
    short* Ws   = (short*)pool;
    short* xs   = (short*)(pool + 20480);
    float* cfl  = (float*)(pool + 26880);
    float* comb = (float*)(pool + 20480);

    const int tid   = threadIdx.x;
    const int wv    = tid >> 6;
    const int lane  = tid & 63;
    const int b     = lane & 15;    // D col = b; A-frag m (=d) also uses lane&15
    const int quad  = lane >> 4;
    const int chunk = blockIdx.x;
    const int gb0   = blockIdx.y * B_TILE;
    const int c0    = chunk * C_PER;

    // ---- stage x once: [16b][24c][8i] f32 -> bf16 LDS, coalesced float4 ----
    {
        const float4* x4 = reinterpret_cast<const float4*>(x);
        #pragma unroll
        for (int it = 0; it < 3; ++it) {
            int e = (tid + BLOCK * it) * 4;
            int b2 = e / 192, r = e - b2 * 192;
            float4 v = x4[((size_t)(gb0 + b2) * (C_N * I_N) + c0 * I_N + r) >> 2];
            *reinterpret_cast<uint2*>(xs + b2 * 200 + r) =
                make_uint2(pack2(v.x, v.y), pack2(v.z, v.w));
        }
    }

    // ---- vsum fragments: vs[n][r] = vsum[gb0+b][n][quad*4+r] (f32, pass-resident) ----
    v4f vs[N_N];
    if (!FIRST) {
        #pragma unroll
        for (int n = 0; n < N_N; ++n) {
            const float4 t = *reinterpret_cast<const float4*>(
                vsum + (((size_t)(gb0 + b) * N_N + n) * D_N + quad * 4));
            vs[n] = (v4f){t.x, t.y, t.z, t.w};
        }
    }

    const int ncnt = (wv < 2) ? 3 : 2;   // wave wv owns n = wv, wv+4, (wv+8)
    v4f sacc[3];
    sacc[0] = (v4f){0.f, 0.f, 0.f, 0.f};
    sacc[1] = (v4f){0.f, 0.f, 0.f, 0.f};
    sacc[2] = (v4f){0.f, 0.f, 0.f, 0.f};

    const float4* W4 = reinterpret_cast<const float4*>(W);

    for (int st = 0; st < N_STAGES; ++st) {
        __syncthreads();   // prior sweep2 reads done; x staging done (st=0)
        // ---- stage W: 8 c's fp32 -> bf16 Ws[c][n][d][i], coalesced ----
        #pragma unroll
        for (int it = 0; it < 10; ++it) {
            int e = (tid + BLOCK * it) * 4;
            int n = e >> 10, rr = e & 1023;
            int c = rr >> 7, k = rr & 127;
            float4 v = W4[((size_t)n * (C_N * 128) + (size_t)(c0 + st * STAGE_C + c) * 128 + k) >> 2];
            *reinterpret_cast<uint2*>(Ws + c * 1280 + n * 128 + k) =
                make_uint2(pack2(v.x, v.y), pack2(v.z, v.w));
        }
        __syncthreads();

        if (!FIRST) {
            // ---- sweep1: this wave's c's: cl = wv + 4t ----
            #pragma unroll
            for (int t = 0; t < 2; ++t) {
                const int cl = wv + 4 * t;
                const v8s xb = *reinterpret_cast<const v8s*>(
                    xs + b * 200 + (st * STAGE_C + cl) * 8);   // k<8 real; k>=8 killed by A=0
                float lg[N_N];
                #pragma unroll
                for (int n = 0; n < N_N; ++n) {
                    v8s wa = {0, 0, 0, 0, 0, 0, 0, 0};
                    if (quad == 0)   // only quad0 holds real k=0..7 (i); rest zero-pad
                        wa = *reinterpret_cast<const v8s*>(Ws + cl * 1280 + n * 128 + b * 8);
                    v4f u = __builtin_amdgcn_mfma_f32_16x16x32_bf16(
                        wa, xb, (v4f){0.f, 0.f, 0.f, 0.f}, 0, 0, 0);
                    float l = u[0] * vs[n][0] + u[1] * vs[n][1]
                            + u[2] * vs[n][2] + u[3] * vs[n][3];
                    l += __shfl_xor(l, 16);
                    l += __shfl_xor(l, 32);
                    lg[n] = l;
                }
                float Z = 0.f;
                #pragma unroll
                for (int n = 0; n < N_N; ++n) { lg[n] = __expf(lg[n]); Z += lg[n]; }
                const float rz = __builtin_amdgcn_rcpf(Z);
                #pragma unroll
                for (int k = 0; k < 3; ++k) {     // distributed: quad q writes n=4k+q
                    int n = 4 * k + quad;
                    if (n < N_N) cfl[cl * 163 + n * 16 + b] = lg[n] * rz;
                }
            }
        }
        __syncthreads();   // coef ready for all c's of this stage

        // ---- sweep2: c-quads; lane's c' = quad; full K=32 = 4c x 8i ----
        #pragma unroll
        for (int Q = 0; Q < 2; ++Q) {
            const int clq   = Q * 4 + quad;
            const int cfull = st * STAGE_C + clq;
            const v8s xq = *reinterpret_cast<const v8s*>(xs + b * 200 + cfull * 8);
            float xf[8];
            #pragma unroll
            for (int j = 0; j < 8; ++j) xf[j] = bf2f(xq[j]);
            #pragma unroll
            for (int jj = 0; jj < 3; ++jj) {
                if (jj < ncnt) {
                    const int n = wv + 4 * jj;
                    const float cv = FIRST ? 0.1f : cfl[clq * 163 + n * 16 + b];
                    union { v8s s; uint32_t u[4]; } zu;
                    zu.u[0] = pack2(cv * xf[0], cv * xf[1]);
                    zu.u[1] = pack2(cv * xf[2], cv * xf[3]);
                    zu.u[2] = pack2(cv * xf[4], cv * xf[5]);
                    zu.u[3] = pack2(cv * xf[6], cv * xf[7]);
                    const v8s wa = *reinterpret_cast<const v8s*>(
                        Ws + clq * 1280 + n * 128 + b * 8);
                    sacc[jj] = __builtin_amdgcn_mfma_f32_16x16x32_bf16(
                        wa, zu.s, sacc[jj], 0, 0, 0);
                }
            }
        }
    }

    __syncthreads();   // all xs/cfl reads done -> comb alias safe
    #pragma unroll
    for (int jj = 0; jj < 3; ++jj) {
        if (jj < ncnt) {
            const int n = wv + 4 * jj;
            #pragma unroll
            for (int r = 0; r < 4; ++r)
                comb[b * 163 + n * 16 + quad * 4 + r] = sacc[jj][r];
        }
    }
    __syncthreads();
    // ---- drain comb -> p_s[chunk][b][n][d] (coalesced) ----
    #pragma unroll
    for (int k = 0; k < 10; ++k) {
        int e = tid + BLOCK * k;          // 0..2559 = bb*160 + n*16 + d
        int bb = e / 160, rem = e - bb * 160;
        p_s[((size_t)chunk * B_N + gb0 + bb) * 160 + rem] = comb[bb * 163 + rem];
    }
}

// Parallel reduce+squash (R4, proven): wave per group g = b*10+n; lane = h*16?? --
// lane = h*4+q; h: 16 chunk-slices x3, q: float4 over d. phase0 vsum=v; 1 +=; 2 out=v.
__global__ __launch_bounds__(BLOCK)
void reduce_squash(const float* __restrict__ p_s, float* __restrict__ vsum,
                   float* __restrict__ out, int phase)
{
    const int warp = threadIdx.x >> 6;
    const int lane = threadIdx.x & 63;
    const int g    = blockIdx.x * 4 + warp;   // 0..2559 == b*10+n
    const int q    = lane & 3;
    const int h    = lane >> 2;

    float4 s = make_float4(0.f, 0.f, 0.f, 0.f);
    #pragma unroll
    for (int m = 0; m < C_CHUNKS / 16; ++m) {
        const int cc = h + 16 * m;
        float4 v = *reinterpret_cast<const float4*>(
            &p_s[((size_t)cc * (B_N * N_N) + g) * D_N + q * 4]);
        s.x += v.x; s.y += v.y; s.z += v.z; s.w += v.w;
    }
    #pragma unroll
    for (int off = 4; off < 64; off <<= 1) {
        s.x += __shfl_xor(s.x, off);
        s.y += __shfl_xor(s.y, off);
        s.z += __shfl_xor(s.z, off);
        s.w += __shfl_xor(s.w, off);
    }
    float sq = s.x * s.x + s.y * s.y + s.z * s.z + s.w * s.w;
    sq += __shfl_xor(sq, 1);
    sq += __shfl_xor(sq, 2);

    const float scale = (sq / (1.f + sq)) / (sqrtf(sq) + 1e-8f);
    const float4 v = make_float4(scale * s.x, scale * s.y, scale * s.z, scale * s.w);

    if (h == 0) {
        if (phase == 0) {
            *reinterpret_cast<float4*>(&vsum[(size_t)g * D_N + q * 4]) = v;
        } else if (phase == 1) {
            float4 o = *reinterpret_cast<const float4*>(&vsum[(size_t)g * D_N + q * 4]);
            *reinterpret_cast<float4*>(&vsum[(size_t)g * D_N + q * 4]) =
                make_float4(o.x + v.x, o.y + v.y, o.z + v.z, o.w + v.w);
        } else {
            *reinterpret_cast<float4*>(&out[(size_t)g * D_N + q * 4]) = v;
        }
    }
}

extern "C" void kernel_launch(void* const* d_in, const int* in_sizes, int n_in,
                              void* d_out, int out_size, void* d_ws, size_t ws_size,
                              hipStream_t stream)
{
    const float* x = (const float*)d_in[0];
    const float* W = (const float*)d_in[1];
    float* out  = (float*)d_out;
    float* vsum = (float*)d_ws;                         // B*N*D floats
    float* p_s  = vsum + (size_t)B_N * N_N * D_N;       // C_CHUNKS*B*N*D floats (~7.9 MB)

    dim3 grid(C_CHUNKS, B_N / B_TILE);
    dim3 blk(BLOCK);
    dim3 rgrid((B_N * N_N) / 4);

    // pass 0: coef = 1/N (softmax of zero logits) -> v0
    route_pass<true><<<grid, blk, 0, stream>>>(x, W, nullptr, p_s);
    reduce_squash<<<rgrid, blk, 0, stream>>>(p_s, vsum, out, 0);
    // pass 1: logits = dot(u_hat, v0) -> v1, vsum = v0+v1
    route_pass<false><<<grid, blk, 0, stream>>>(x, W, vsum, p_s);
    reduce_squash<<<rgrid, blk, 0, stream>>>(p_s, vsum, out, 1);
    // pass 2: logits = dot(u_hat, v0+v1) -> output v2
    route_pass<false><<<grid, blk, 0, stream>>>(x, W, vsum, p_s);
    reduce_squash<<<rgrid, blk, 0, stream>>>(p_s, vsum, out, 2);
}

// Round 6
// 134.772 us; speedup vs baseline: 1.6016x; 1.0134x over previous
//
#include <hip/hip_runtime.h>
#include <math.h>
#include <stdint.h>

// Problem dims (fixed by setup_inputs)
#define B_N 256
#define C_N 1152
#define I_N 8
#define N_N 10
#define D_N 16

constexpr int C_CHUNKS = 48;             // parallelism over the c-reduction
constexpr int C_PER    = 24;             // c's per block
constexpr int STAGE_C  = 12;             // c's per W staging round
constexpr int N_STAGES = 2;
constexpr int B_TILE   = 16;             // batch elements per block (one MFMA tile)
constexpr int BLOCK    = 256;

typedef short v8s __attribute__((ext_vector_type(8)));   // 8 bf16 (4 VGPRs) MFMA A/B frag
typedef float v4f __attribute__((ext_vector_type(4)));   // 4 f32 MFMA C/D frag

// LDS pool (bytes):
//   Ws  (short): [12c][10n][16d][8i]  c-stride 1280 shorts -> 30720 B @ 0
//   xs  (short): [16b][200] (24c*8i + 8 pad)               ->  6400 B @ 30720
//   cfl (float): [12c][163] (10n*16b + 3 pad)              ->  7824 B @ 37120
//   comb(float): [16b][163] ALIASES xs+cfl                 -> 10432 B @ 30720
constexpr int POOL_BYTES = 30720 + 6400 + 7824;  // 44944 -> 3 blocks/CU (grid is 3/CU anyway)

__device__ __forceinline__ uint32_t bf16_rne(float f) {
    uint32_t u = __float_as_uint(f);
    return (u + 0x7FFFu + ((u >> 16) & 1u)) >> 16;
}
__device__ __forceinline__ uint32_t pack2(float a, float b) {
    return bf16_rne(a) | (bf16_rne(b) << 16);
}
__device__ __forceinline__ float bf2f(short s) {
    return __uint_as_float(((uint32_t)(uint16_t)s) << 16);
}

// One routing pass via MFMA. D[row=(lane>>4)*4+reg -> d][col=lane&15 -> b].
// Sweep1: per (c,n) one K-padded MFMA -> u[d,b]; logit = u . vsum (regs) + 2 shfl;
//         exp STREAMED to cfl (owning quad), running Z in reg, post-scale by rcp(Z)
//         (removes the lg[10] register array -> no spills under the 170-VGPR budget).
// Sweep2: B-frag = bf16(coef*x) in regs; s[d,b] accumulates in C-frag per n
//         (waves own n-subsets) over all 24 c's.
// FIRST: coef = 0.1 (softmax of zeros) -> sweep2 only, no vsum read.
template <bool FIRST>
__global__ __launch_bounds__(BLOCK, 3)
void route_pass(const float* __restrict__ x, const float* __restrict__ W,
                const float* __restrict__ vsum, float* __restrict__ p_s)
{
    __shared__ __align__(16) char pool[POOL_BYTES];
    short* Ws   = (short*)pool;
    short* xs   = (short*)(pool + 30720);
    float* cfl  = (float*)(pool + 37120);
    float* comb = (float*)(pool + 30720);

    const int tid   = threadIdx.x;
    const int wv    = tid >> 6;
    const int lane  = tid & 63;
    const int b     = lane & 15;    // D col = b; A-frag m (=d) also uses lane&15
    const int quad  = lane >> 4;
    const int chunk = blockIdx.x;
    const int gb0   = blockIdx.y * B_TILE;
    const int c0    = chunk * C_PER;

    // ---- stage x once: [16b][24c][8i] f32 -> bf16 LDS, coalesced float4 ----
    {
        const float4* x4 = reinterpret_cast<const float4*>(x);
        #pragma unroll
        for (int it = 0; it < 3; ++it) {
            int e = (tid + BLOCK * it) * 4;
            int b2 = e / 192, r = e - b2 * 192;
            float4 v = x4[((size_t)(gb0 + b2) * (C_N * I_N) + c0 * I_N + r) >> 2];
            *reinterpret_cast<uint2*>(xs + b2 * 200 + r) =
                make_uint2(pack2(v.x, v.y), pack2(v.z, v.w));
        }
    }

    // ---- vsum fragments: vs[n][r] = vsum[gb0+b][n][quad*4+r] (f32, pass-resident) ----
    v4f vs[N_N];
    if (!FIRST) {
        #pragma unroll
        for (int n = 0; n < N_N; ++n) {
            const float4 t = *reinterpret_cast<const float4*>(
                vsum + (((size_t)(gb0 + b) * N_N + n) * D_N + quad * 4));
            vs[n] = (v4f){t.x, t.y, t.z, t.w};
        }
    }

    const int ncnt = (wv < 2) ? 3 : 2;   // wave wv owns n = wv, wv+4, (wv+8)
    v4f sacc[3];
    sacc[0] = (v4f){0.f, 0.f, 0.f, 0.f};
    sacc[1] = (v4f){0.f, 0.f, 0.f, 0.f};
    sacc[2] = (v4f){0.f, 0.f, 0.f, 0.f};

    const float4* W4 = reinterpret_cast<const float4*>(W);

    for (int st = 0; st < N_STAGES; ++st) {
        __syncthreads();   // prior sweep2 Ws/cfl reads done; x staging done (st=0)
        // ---- stage W: 12 c's fp32 -> bf16 Ws[c][n][d][i], coalesced ----
        #pragma unroll
        for (int it = 0; it < 15; ++it) {
            int e = (tid + BLOCK * it) * 4;
            int n = e / 1536, rr = e - n * 1536;
            int c = rr >> 7, k = rr & 127;
            float4 v = W4[((size_t)n * (C_N * 128) + (size_t)(c0 + st * STAGE_C + c) * 128 + k) >> 2];
            *reinterpret_cast<uint2*>(Ws + c * 1280 + n * 128 + k) =
                make_uint2(pack2(v.x, v.y), pack2(v.z, v.w));
        }
        __syncthreads();

        if (!FIRST) {
            // ---- sweep1: this wave's c's: cl = wv + 4t ----
            #pragma unroll
            for (int t = 0; t < 3; ++t) {
                const int cl = wv + 4 * t;
                const v8s xb = *reinterpret_cast<const v8s*>(
                    xs + b * 200 + (st * STAGE_C + cl) * 8);   // k<8 real; k>=8 killed by A=0
                float Z = 0.f;
                #pragma unroll
                for (int n = 0; n < N_N; ++n) {
                    v8s wa = {0, 0, 0, 0, 0, 0, 0, 0};
                    if (quad == 0)   // only quad0 holds real k=0..7 (i); rest zero-pad
                        wa = *reinterpret_cast<const v8s*>(Ws + cl * 1280 + n * 128 + b * 8);
                    v4f u = __builtin_amdgcn_mfma_f32_16x16x32_bf16(
                        wa, xb, (v4f){0.f, 0.f, 0.f, 0.f}, 0, 0, 0);
                    float l = u[0] * vs[n][0] + u[1] * vs[n][1]
                            + u[2] * vs[n][2] + u[3] * vs[n][3];
                    l += __shfl_xor(l, 16);
                    l += __shfl_xor(l, 32);
                    // |l| <~ 3 -> exp safe without max subtraction
                    const float e1 = __expf(l);
                    Z += e1;
                    if ((n & 3) == quad)            // owning quad streams exp to LDS
                        cfl[cl * 163 + n * 16 + b] = e1;
                }
                const float rz = __builtin_amdgcn_rcpf(Z);
                #pragma unroll
                for (int jj = 0; jj < 3; ++jj) {    // scale own n's by 1/Z in-place
                    int n = 4 * jj + quad;
                    if (n < N_N) cfl[cl * 163 + n * 16 + b] *= rz;
                }
            }
        }
        __syncthreads();   // coef ready for all c's of this stage

        // ---- sweep2: lane's c = Q*4+quad; full K=32 = 4c-pack x 8i per n-owner wave ----
        #pragma unroll
        for (int Q = 0; Q < 3; ++Q) {
            const int clq   = Q * 4 + quad;
            const int cfull = st * STAGE_C + clq;
            const v8s xq = *reinterpret_cast<const v8s*>(xs + b * 200 + cfull * 8);
            float xf[8];
            #pragma unroll
            for (int j = 0; j < 8; ++j) xf[j] = bf2f(xq[j]);
            #pragma unroll
            for (int jj = 0; jj < 3; ++jj) {
                if (jj < ncnt) {
                    const int n = wv + 4 * jj;
                    const float cv = FIRST ? 0.1f : cfl[clq * 163 + n * 16 + b];
                    union { v8s s; uint32_t u[4]; } zu;
                    zu.u[0] = pack2(cv * xf[0], cv * xf[1]);
                    zu.u[1] = pack2(cv * xf[2], cv * xf[3]);
                    zu.u[2] = pack2(cv * xf[4], cv * xf[5]);
                    zu.u[3] = pack2(cv * xf[6], cv * xf[7]);
                    const v8s wa = *reinterpret_cast<const v8s*>(
                        Ws + clq * 1280 + n * 128 + b * 8);
                    sacc[jj] = __builtin_amdgcn_mfma_f32_16x16x32_bf16(
                        wa, zu.s, sacc[jj], 0, 0, 0);
                }
            }
        }
    }

    __syncthreads();   // all xs/cfl reads done -> comb alias safe
    #pragma unroll
    for (int jj = 0; jj < 3; ++jj) {
        if (jj < ncnt) {
            const int n = wv + 4 * jj;
            #pragma unroll
            for (int r = 0; r < 4; ++r)
                comb[b * 163 + n * 16 + quad * 4 + r] = sacc[jj][r];
        }
    }
    __syncthreads();
    // ---- drain comb -> p_s[chunk][b][n][d] (coalesced) ----
    #pragma unroll
    for (int k = 0; k < 10; ++k) {
        int e = tid + BLOCK * k;          // 0..2559 = bb*160 + n*16 + d
        int bb = e / 160, rem = e - bb * 160;
        p_s[((size_t)chunk * B_N + gb0 + bb) * 160 + rem] = comb[bb * 163 + rem];
    }
}

// Parallel reduce+squash: wave per group g = b*10+n; lane = h*4+q; h: 16 chunk-
// slices x3, q: float4 over d. phase0 vsum=v; phase1 vsum+=v; phase2 out=v.
__global__ __launch_bounds__(BLOCK)
void reduce_squash(const float* __restrict__ p_s, float* __restrict__ vsum,
                   float* __restrict__ out, int phase)
{
    const int warp = threadIdx.x >> 6;
    const int lane = threadIdx.x & 63;
    const int g    = blockIdx.x * 4 + warp;   // 0..2559 == b*10+n
    const int q    = lane & 3;
    const int h    = lane >> 2;

    float4 s = make_float4(0.f, 0.f, 0.f, 0.f);
    #pragma unroll
    for (int m = 0; m < C_CHUNKS / 16; ++m) {
        const int cc = h + 16 * m;
        float4 v = *reinterpret_cast<const float4*>(
            &p_s[((size_t)cc * (B_N * N_N) + g) * D_N + q * 4]);
        s.x += v.x; s.y += v.y; s.z += v.z; s.w += v.w;
    }
    #pragma unroll
    for (int off = 4; off < 64; off <<= 1) {
        s.x += __shfl_xor(s.x, off);
        s.y += __shfl_xor(s.y, off);
        s.z += __shfl_xor(s.z, off);
        s.w += __shfl_xor(s.w, off);
    }
    float sq = s.x * s.x + s.y * s.y + s.z * s.z + s.w * s.w;
    sq += __shfl_xor(sq, 1);
    sq += __shfl_xor(sq, 2);

    const float scale = (sq / (1.f + sq)) / (sqrtf(sq) + 1e-8f);
    const float4 v = make_float4(scale * s.x, scale * s.y, scale * s.z, scale * s.w);

    if (h == 0) {
        if (phase == 0) {
            *reinterpret_cast<float4*>(&vsum[(size_t)g * D_N + q * 4]) = v;
        } else if (phase == 1) {
            float4 o = *reinterpret_cast<const float4*>(&vsum[(size_t)g * D_N + q * 4]);
            *reinterpret_cast<float4*>(&vsum[(size_t)g * D_N + q * 4]) =
                make_float4(o.x + v.x, o.y + v.y, o.z + v.z, o.w + v.w);
        } else {
            *reinterpret_cast<float4*>(&out[(size_t)g * D_N + q * 4]) = v;
        }
    }
}

extern "C" void kernel_launch(void* const* d_in, const int* in_sizes, int n_in,
                              void* d_out, int out_size, void* d_ws, size_t ws_size,
                              hipStream_t stream)
{
    const float* x = (const float*)d_in[0];
    const float* W = (const float*)d_in[1];
    float* out  = (float*)d_out;
    float* vsum = (float*)d_ws;                         // B*N*D floats
    float* p_s  = vsum + (size_t)B_N * N_N * D_N;       // C_CHUNKS*B*N*D floats (~7.9 MB)

    dim3 grid(C_CHUNKS, B_N / B_TILE);
    dim3 blk(BLOCK);
    dim3 rgrid((B_N * N_N) / 4);

    // pass 0: coef = 1/N (softmax of zero logits) -> v0
    route_pass<true><<<grid, blk, 0, stream>>>(x, W, nullptr, p_s);
    reduce_squash<<<rgrid, blk, 0, stream>>>(p_s, vsum, out, 0);
    // pass 1: logits = dot(u_hat, v0) -> v1, vsum = v0+v1
    route_pass<false><<<grid, blk, 0, stream>>>(x, W, vsum, p_s);
    reduce_squash<<<rgrid, blk, 0, stream>>>(p_s, vsum, out, 1);
    // pass 2: logits = dot(u_hat, v0+v1) -> output v2
    route_pass<false><<<grid, blk, 0, stream>>>(x, W, vsum, p_s);
    reduce_squash<<<rgrid, blk, 0, stream>>>(p_s, vsum, out, 2);
}